// Round 3
// baseline (1266.673 us; speedup 1.0000x reference)
//
#include <hip/hip_runtime.h>
#include <hip/hip_bf16.h>

// Sizes
#define BB 64
#define LL 25
#define DD 128
#define BL 1600           // B*L
#define POI_N 10000
#define CAT_N 400

// ---------------------------------------------------------------------------
// Embedding gather + zero-init of sbm slots (8 insts x 32) and min/max slots.
// ---------------------------------------------------------------------------
__global__ __launch_bounds__(256) void embed_kernel(
    const int* __restrict__ user, const int* __restrict__ poi, const int* __restrict__ cat,
    const int* __restrict__ tod, const int* __restrict__ dow,
    const float* __restrict__ ue, const float* __restrict__ pe, const float* __restrict__ ce,
    const float* __restrict__ te, const float* __restrict__ de,
    const float* __restrict__ uec, const float* __restrict__ tec, const float* __restrict__ dec,
    float* __restrict__ x, float* __restrict__ xc,
    float* __restrict__ sbm_all, unsigned* __restrict__ mm)
{
    int idx = blockIdx.x * 256 + threadIdx.x;           // 0 .. 204799 exactly
    if (idx < 256) sbm_all[idx] = 0.0f;                 // 8 insts x 32 slots
    if (idx == 0) { mm[0] = 0u; mm[1] = 0x7f7fffffu; }  // gmax=0.0f, gmin=FLT_MAX (all D>=0)
    int bl = idx >> 7, d = idx & 127;
    int u = user[bl], p = poi[bl], c = cat[bl], td = tod[bl], dw = dow[bl];
    x[idx]  = ue[u * DD + d] + pe[p * DD + d] + te[td * DD + d] + de[dw * DD + d];
    xc[idx] = uec[u * DD + d] + ce[c * DD + d] + tec[td * DD + d] + dec[dw * DD + d];
}

// ---------------------------------------------------------------------------
// Global max/min over the 1600 gathered distance rows.
// ---------------------------------------------------------------------------
__global__ __launch_bounds__(256) void minmax_kernel(
    const int* __restrict__ poi, const float* __restrict__ Dm, unsigned* __restrict__ mm)
{
    int bl = blockIdx.x;
    const float4* r = (const float4*)(Dm + (size_t)poi[bl] * POI_N);
    float mx = -1e30f, mn = 1e30f;
    for (int i = threadIdx.x; i < POI_N / 4; i += 256) {
        float4 v4 = r[i];
        mx = fmaxf(mx, fmaxf(fmaxf(v4.x, v4.y), fmaxf(v4.z, v4.w)));
        mn = fminf(mn, fminf(fminf(v4.x, v4.y), fminf(v4.z, v4.w)));
    }
    for (int off = 32; off > 0; off >>= 1) {
        mx = fmaxf(mx, __shfl_down(mx, off));
        mn = fminf(mn, __shfl_down(mn, off));
    }
    __shared__ float smx[4], smn[4];
    int lid = threadIdx.x & 63, wid = threadIdx.x >> 6;
    if (lid == 0) { smx[wid] = mx; smn[wid] = mn; }
    __syncthreads();
    if (threadIdx.x == 0) {
        mx = fmaxf(fmaxf(smx[0], smx[1]), fmaxf(smx[2], smx[3]));
        mn = fminf(fminf(smn[0], smn[1]), fminf(smn[2], smn[3]));
        atomicMax(&mm[0], __float_as_uint(mx));
        atomicMin(&mm[1], __float_as_uint(mn));
    }
}

// ---------------------------------------------------------------------------
// In-LDS 25x128 @ 128x128^T GEMM helper. sX: input rows (padded 132),
// sW: 128x36 staging (stride 36 == 4 mod 32 -> conflict-optimal b128),
// W staged in four K=32 chunks. Rows per thread: {mg, mg+8, mg+16} (+24 for
// mg==0); cols nh+32j. Epilogue to LDS (sDst) or global (gRow).
// Caller must __syncthreads() after return before reading the output.
// ---------------------------------------------------------------------------
template<bool TO_LDS>
__device__ __forceinline__ void gemm25(const float (*sX)[132], float (*sW)[36],
                                       const float* __restrict__ Wm,
                                       const float* __restrict__ bias,
                                       float (*sDst)[132], float* __restrict__ gRow, int t)
{
    int nh = t & 31, mg = t >> 5;
    float acc[4][4] = {};
    for (int kb = 0; kb < DD; kb += 32) {
        for (int i = t; i < 128 * 8; i += 256) {
            int n = i >> 3, c = (i & 7) << 2;
            *(float4*)&sW[n][c] = *(const float4*)(Wm + n * DD + kb + c);
        }
        __syncthreads();
#pragma unroll
        for (int kk = 0; kk < 32; kk += 4) {
            float4 a0 = *(const float4*)&sX[mg][kb + kk];
            float4 a1 = *(const float4*)&sX[mg + 8][kb + kk];
            float4 a2 = *(const float4*)&sX[mg + 16][kb + kk];
            float4 a3 = {0.f, 0.f, 0.f, 0.f};
            if (mg == 0) a3 = *(const float4*)&sX[24][kb + kk];
#pragma unroll
            for (int j = 0; j < 4; j++) {
                float4 w4 = *(const float4*)&sW[nh + 32 * j][kk];
                acc[j][0] += w4.x * a0.x + w4.y * a0.y + w4.z * a0.z + w4.w * a0.w;
                acc[j][1] += w4.x * a1.x + w4.y * a1.y + w4.z * a1.z + w4.w * a1.w;
                acc[j][2] += w4.x * a2.x + w4.y * a2.y + w4.z * a2.z + w4.w * a2.w;
                acc[j][3] += w4.x * a3.x + w4.y * a3.y + w4.z * a3.z + w4.w * a3.w;
            }
        }
        __syncthreads();
    }
#pragma unroll
    for (int j = 0; j < 4; j++) {
        int n = nh + 32 * j;
        float bj = bias[n];
        if (TO_LDS) {
            sDst[mg][n]      = acc[j][0] + bj;
            sDst[mg + 8][n]  = acc[j][1] + bj;
            sDst[mg + 16][n] = acc[j][2] + bj;
            if (mg == 0) sDst[24][n] = acc[j][3] + bj;
        } else {
            gRow[mg * DD + n]        = acc[j][0] + bj;
            gRow[(mg + 8) * DD + n]  = acc[j][1] + bj;
            gRow[(mg + 16) * DD + n] = acc[j][2] + bj;
            if (mg == 0) gRow[24 * DD + n] = acc[j][3] + bj;
        }
    }
}

struct AcArgs {
    const float* qx; const float* kx; const float* vx;
    const float* Wb;   // 4 x 128 x 128 (q,k,v,o)
    const float* Bb;   // 4 x 128
    float* dst;        // 1600 x 128 output of this ac
    float* mv;         // 64 x 25 per-b mean_value
    float* sbm;        // 32 (batch-sum slot, zeroed in embed)
};

// ---------------------------------------------------------------------------
// AC1: per (b, problem): Q = qx@Wq^T+bq, K = kx@Wk^T+bk (both LDS-only),
// mv[b,tau] = (1/128) sum_s Q[(s+tau)%25].K[s]; atomicAdd batch-sum.
// ---------------------------------------------------------------------------
__global__ __launch_bounds__(256) void ac1_kernel(AcArgs a0, AcArgs a1)
{
    const AcArgs a = blockIdx.y ? a1 : a0;
    int b = blockIdx.x, t = threadIdx.x;
    __shared__ float sX[LL][132];
    __shared__ float sW[128][36];
    __shared__ float sQ[LL][132];
    __shared__ float sK[LL][132];
    __shared__ float rbuf[LL][4];

    for (int f = t; f < 800; f += 256) {
        int l = f >> 5, c = (f & 31) << 2;
        *(float4*)&sX[l][c] = *(const float4*)(a.qx + (b * LL + l) * DD + c);
    }
    __syncthreads();
    gemm25<true>(sX, sW, a.Wb, a.Bb, sQ, nullptr, t);
    // restage kx (gemm's trailing sync guarantees sX reads are done)
    for (int f = t; f < 800; f += 256) {
        int l = f >> 5, c = (f & 31) << 2;
        *(float4*)&sX[l][c] = *(const float4*)(a.kx + (b * LL + l) * DD + c);
    }
    __syncthreads();   // covers sQ writes + sX restage
    gemm25<true>(sX, sW, a.Wb + DD * DD, a.Bb + DD, sK, nullptr, t);
    __syncthreads();   // sK visible

    int lid = t & 63, wid = t >> 6;
    for (int tau = 0; tau < LL; tau++) {
        float s = 0.f;
        for (int e = t; e < LL * DD; e += 256) {
            int sr = e >> 7, d = e & 127;
            int qr = sr + tau; if (qr >= LL) qr -= LL;
            s += sQ[qr][d] * sK[sr][d];
        }
        for (int off = 32; off > 0; off >>= 1) s += __shfl_down(s, off);
        if (lid == 0) rbuf[tau][wid] = s;
    }
    __syncthreads();
    if (t < LL) {
        float v = (rbuf[t][0] + rbuf[t][1] + rbuf[t][2] + rbuf[t][3]) * (1.0f / 128.0f);
        a.mv[b * LL + t] = v;
        atomicAdd(&a.sbm[t], v);
    }
}

// ---------------------------------------------------------------------------
// AC2: per (b, problem): top-3 of batch-summed mv (redundant per block,
// wave 0) + per-b softmax; V = vx@Wv^T+bv (LDS); agg = shift-gather of V;
// dst = agg@Wo^T+bo (global).
// ---------------------------------------------------------------------------
__global__ __launch_bounds__(256) void ac2_kernel(AcArgs a0, AcArgs a1)
{
    const AcArgs a = blockIdx.y ? a1 : a0;
    int b = blockIdx.x, t = threadIdx.x;
    __shared__ float sX[LL][132];
    __shared__ float sW[128][36];
    __shared__ float sV[LL][132];
    __shared__ float sA[LL][132];
    __shared__ int sidx[3];
    __shared__ float sTc[3];

    if (t < 64) {  // wave 0: top-3 (strict > keeps lowest index, like top_k)
        float v = (t < LL) ? a.sbm[t] : -3e38f;
        for (int r = 0; r < 3; r++) {
            float bv = v; int bix = t;
            for (int off = 32; off > 0; off >>= 1) {
                float ov = __shfl_down(bv, off);
                int   oi = __shfl_down(bix, off);
                if (ov > bv) { bv = ov; bix = oi; }
            }
            bix = __shfl(bix, 0);
            if (t == 0) sidx[r] = bix;
            if (t == bix) v = -3e38f;
        }
        if (t == 0) {
            float w0 = a.mv[b * LL + sidx[0]];
            float w1 = a.mv[b * LL + sidx[1]];
            float w2 = a.mv[b * LL + sidx[2]];
            float m = fmaxf(w0, fmaxf(w1, w2));
            float e0 = expf(w0 - m), e1 = expf(w1 - m), e2 = expf(w2 - m);
            float inv = 1.0f / (e0 + e1 + e2);
            sTc[0] = e0 * inv; sTc[1] = e1 * inv; sTc[2] = e2 * inv;
        }
    }
    for (int f = t; f < 800; f += 256) {
        int l = f >> 5, c = (f & 31) << 2;
        *(float4*)&sX[l][c] = *(const float4*)(a.vx + (b * LL + l) * DD + c);
    }
    __syncthreads();
    gemm25<true>(sX, sW, a.Wb + 2 * DD * DD, a.Bb + 2 * DD, sV, nullptr, t);
    __syncthreads();   // sV visible

    int i0 = sidx[0], i1 = sidx[1], i2 = sidx[2];
    float w0 = sTc[0], w1 = sTc[1], w2 = sTc[2];
    for (int f = t; f < 800; f += 256) {
        int l = f >> 5, c = (f & 31) << 2;
        int l0 = l + i0; if (l0 >= LL) l0 -= LL;
        int l1 = l + i1; if (l1 >= LL) l1 -= LL;
        int l2 = l + i2; if (l2 >= LL) l2 -= LL;
        float4 v0 = *(const float4*)&sV[l0][c];
        float4 v1 = *(const float4*)&sV[l1][c];
        float4 v2 = *(const float4*)&sV[l2][c];
        float4 r;
        r.x = w0 * v0.x + w1 * v1.x + w2 * v2.x;
        r.y = w0 * v0.y + w1 * v1.y + w2 * v2.y;
        r.z = w0 * v0.z + w1 * v1.z + w2 * v2.z;
        r.w = w0 * v0.w + w1 * v1.w + w2 * v2.w;
        *(float4*)&sA[l][c] = r;
    }
    __syncthreads();
    gemm25<false>(sA, sW, a.Wb + 3 * DD * DD, a.Bb + 3 * DD, nullptr,
                  a.dst + b * LL * DD, t);
}

// ---------------------------------------------------------------------------
// pre_cat[b,c] = cat_emb[c] . (sum_l vw[l]*outc[b,l,:]) + vb
// ---------------------------------------------------------------------------
__global__ __launch_bounds__(256) void precat_kernel(
    const float* __restrict__ outc, const float* __restrict__ cat_emb,
    const float* __restrict__ vw, const float* __restrict__ vbp, float* __restrict__ dstc)
{
    int b = blockIdx.x, t = threadIdx.x;
    __shared__ float y[DD];
    __shared__ float svw[LL];
    if (t < LL) svw[t] = vw[t];
    __syncthreads();
    if (t < DD) {
        float s = 0.f;
        for (int l = 0; l < LL; l++) s += svw[l] * outc[(b * LL + l) * DD + t];
        y[t] = s;
    }
    __syncthreads();
    float vb = vbp[0];
    for (int c = t; c < CAT_N; c += 256) {
        float s = 0.f;
        for (int d = 0; d < DD; d += 4) {
            float4 ce4 = *(const float4*)(cat_emb + c * DD + d);
            s += ce4.x * y[d] + ce4.y * y[d + 1] + ce4.z * y[d + 2] + ce4.w * y[d + 3];
        }
        dstc[b * CAT_N + c] = s + vb;
    }
}

// ---------------------------------------------------------------------------
// pre_poi[b,p] = vb + sum_l vw[l]*exp(-D[poi[b,l],p]/(gmax-gmin))*(poi_emb[p].out[b,l,:])
// ---------------------------------------------------------------------------
__global__ __launch_bounds__(256) void prepoi_kernel(
    const float* __restrict__ outp, const float* __restrict__ poi_emb,
    const int* __restrict__ poi_idx, const float* __restrict__ Dm,
    const unsigned* __restrict__ mm, const float* __restrict__ vw,
    const float* __restrict__ vbp, float* __restrict__ dstp)
{
    int b = blockIdx.y;
    int pbase = blockIdx.x << 7;
    __shared__ float sO[LL][132];
    __shared__ float sPc[128][68];
    __shared__ float sS[LL][132];
    __shared__ float svw[LL];
    __shared__ int srow[LL];
    __shared__ float red[128];
    int t = threadIdx.x;

    for (int i = t; i < 800; i += 256) {
        int l = i >> 5, c = (i & 31) << 2;
        *(float4*)&sO[l][c] = *(const float4*)(outp + (b * LL + l) * DD + c);
    }
    if (t < LL) { svw[t] = vw[t]; srow[t] = poi_idx[b * LL + t]; }
    __syncthreads();

    int nh = t & 31, mg = t >> 5;
    float acc[4][4] = {};
    for (int kb = 0; kb < 128; kb += 64) {
        for (int i = t; i < 128 * 16; i += 256) {
            int p = i >> 4, c = (i & 15) << 2;
            float4 val = {0.f, 0.f, 0.f, 0.f};
            if (pbase + p < POI_N) val = *(const float4*)(poi_emb + (pbase + p) * DD + kb + c);
            *(float4*)&sPc[p][c] = val;
        }
        __syncthreads();
#pragma unroll 4
        for (int kk = 0; kk < 64; kk += 4) {
            float4 a0 = *(const float4*)&sO[mg][kb + kk];
            float4 a1 = *(const float4*)&sO[mg + 8][kb + kk];
            float4 a2 = *(const float4*)&sO[mg + 16][kb + kk];
            float4 a3 = {0.f, 0.f, 0.f, 0.f};
            if (mg == 0) a3 = *(const float4*)&sO[24][kb + kk];
#pragma unroll
            for (int j = 0; j < 4; j++) {
                float4 p4 = *(const float4*)&sPc[nh + 32 * j][kk];
                acc[j][0] += p4.x * a0.x + p4.y * a0.y + p4.z * a0.z + p4.w * a0.w;
                acc[j][1] += p4.x * a1.x + p4.y * a1.y + p4.z * a1.z + p4.w * a1.w;
                acc[j][2] += p4.x * a2.x + p4.y * a2.y + p4.z * a2.z + p4.w * a2.w;
                acc[j][3] += p4.x * a3.x + p4.y * a3.y + p4.z * a3.z + p4.w * a3.w;
            }
        }
        __syncthreads();
    }
#pragma unroll
    for (int j = 0; j < 4; j++) {
        int pl = nh + 32 * j;
        sS[mg][pl]      = acc[j][0];
        sS[mg + 8][pl]  = acc[j][1];
        sS[mg + 16][pl] = acc[j][2];
        if (mg == 0) sS[24][pl] = acc[j][3];
    }
    __syncthreads();

    float gmax = __uint_as_float(mm[0]);
    float gmin = __uint_as_float(mm[1]);
    float ninv = -1.0f / (gmax - gmin);
    int pp = t & 127, half = t >> 7;
    int p = pbase + pp;
    float s = 0.f;
    if (p < POI_N) {
        int l0 = half ? 13 : 0, l1 = half ? 25 : 13;
        for (int l = l0; l < l1; l++) {
            float dv = Dm[(size_t)srow[l] * POI_N + p];
            s += svw[l] * expf(dv * ninv) * sS[l][pp];
        }
    }
    if (half) red[pp] = s;
    __syncthreads();
    if (!half && p < POI_N)
        dstp[(size_t)b * POI_N + p] = s + red[pp] + vbp[0];
}

// ---------------------------------------------------------------------------
extern "C" void kernel_launch(void* const* d_in, const int* in_sizes, int n_in,
                              void* d_out, int out_size, void* d_ws, size_t ws_size,
                              hipStream_t stream)
{
    const int*   user = (const int*)d_in[0];
    const int*   poi  = (const int*)d_in[1];
    const int*   cat  = (const int*)d_in[2];
    const int*   tod  = (const int*)d_in[5];
    const int*   dow  = (const int*)d_in[6];
    const float* ue   = (const float*)d_in[8];
    const float* pe   = (const float*)d_in[9];
    const float* ce   = (const float*)d_in[10];
    const float* te   = (const float*)d_in[11];
    const float* de   = (const float*)d_in[12];
    const float* uec  = (const float*)d_in[13];
    const float* tec  = (const float*)d_in[14];
    const float* dec  = (const float*)d_in[15];
    const float* W    = (const float*)d_in[16];
    const float* Bv   = (const float*)d_in[17];
    const float* vw   = (const float*)d_in[18];
    const float* vb   = (const float*)d_in[19];
    const float* Dm   = (const float*)d_in[20];

    float* ws = (float*)d_ws;
    float* O0 = ws;
    float* C0 = ws + 204800;
    float* O1 = ws + 409600;
    float* C1 = ws + 614400;
    float* MV  = ws + 819200;                  // 8 x 64 x 25
    float* SBM = ws + 832000;                  // 8 x 32 (zeroed in embed)
    unsigned* MM = (unsigned*)(ws + 832256);   // 2

    float* out_poi = (float*)d_out;
    float* out_cat = out_poi + BB * POI_N;

    embed_kernel<<<800, 256, 0, stream>>>(user, poi, cat, tod, dow,
                                          ue, pe, ce, te, de, uec, tec, dec,
                                          O0, C0, SBM, MM);
    minmax_kernel<<<BL, 256, 0, stream>>>(poi, Dm, MM);

    auto mk = [&](int inst, const float* qx, const float* kx, const float* vx,
                  int i, int j, float* dstbuf) -> AcArgs {
        AcArgs a;
        a.qx = qx; a.kx = kx; a.vx = vx;
        a.Wb = W + (size_t)((i * 4 + j) * 4) * DD * DD;
        a.Bb = Bv + (size_t)((i * 4 + j) * 4) * DD;
        a.dst = dstbuf;
        a.mv  = MV + inst * BB * LL;
        a.sbm = SBM + inst * 32;
        return a;
    };

    for (int i = 0; i < 2; i++) {
        // ac1 (O-path) and ac2 (C-path) are independent -> fused dispatch
        AcArgs A0 = mk(4 * i + 0, O0, O0, O0, i, 0, O1);
        AcArgs A1 = mk(4 * i + 1, C0, C0, C0, i, 1, C1);
        ac1_kernel<<<dim3(BB, 2), 256, 0, stream>>>(A0, A1);
        ac2_kernel<<<dim3(BB, 2), 256, 0, stream>>>(A0, A1);
        // ac3: out = ac(out, outc, outc)  — current out=O1, outc=C1
        AcArgs A2 = mk(4 * i + 2, O1, C1, C1, i, 2, O0);
        ac1_kernel<<<dim3(BB, 1), 256, 0, stream>>>(A2, A2);
        ac2_kernel<<<dim3(BB, 1), 256, 0, stream>>>(A2, A2);
        // ac4: outc = ac(outc, out, out) — current outc=C1 (!), out=O0
        AcArgs A3 = mk(4 * i + 3, C1, O0, O0, i, 3, C0);
        ac1_kernel<<<dim3(BB, 1), 256, 0, stream>>>(A3, A3);
        ac2_kernel<<<dim3(BB, 1), 256, 0, stream>>>(A3, A3);
    }

    precat_kernel<<<BB, 256, 0, stream>>>(C0, ce, vw, vb, out_cat);
    prepoi_kernel<<<dim3(79, BB), 256, 0, stream>>>(O0, pe, poi, Dm, MM, vw, vb, out_poi);
}